// Round 5
// baseline (706.971 us; speedup 1.0000x reference)
//
#include <hip/hip_runtime.h>

// ProdAttention: LN -> QKV proj -> per-head top-32 of q.k^T (softmax monotone
// => select on raw sim) -> unweighted gather-sum of selected v rows -> global
// minmax-normalize + exp -> transpose -> output proj + bias.
// All GEMM-shaped compute (QKV, sim, out-proj) on MFMA with f16 hi/lo split
// (3 terms ~ fp32 precision; dropped lo*lo ~2^-22).  Selection fp32-exact
// wave ballots on order-preserving keys (discrete top-k anchors absmax).

#define LN_EPS 1e-5f
static constexpr size_t SZ = 4096ull * 1024ull;

using half8   = __attribute__((ext_vector_type(8))) _Float16;
using half4   = __attribute__((ext_vector_type(4))) _Float16;
using float4v = __attribute__((ext_vector_type(4))) float;

__device__ __forceinline__ void gload_lds16(const void* g, void* l) {
  __builtin_amdgcn_global_load_lds(
      (const __attribute__((address_space(1))) void*)g,
      (__attribute__((address_space(3))) void*)l, 16, 0, 0);
}
__device__ __forceinline__ float4v mfma16(half8 a, half8 b, float4v c) {
  return __builtin_amdgcn_mfma_f32_16x16x32_f16(a, b, c, 0, 0, 0);
}
struct HL { _Float16 h, l; };
__device__ __forceinline__ HL split2(float x) {
  _Float16 h = (_Float16)x;
  return { h, (_Float16)(x - (float)h) };
}

// ---------------- order-preserving key helpers ----------------
__device__ __forceinline__ unsigned fkey(float f) {
  unsigned u = __float_as_uint(f);
  return ((int)u < 0) ? ~u : (u | 0x80000000u);
}
__device__ __forceinline__ int enc_i(float f) {
  int i = __float_as_int(f);
  return i >= 0 ? i : (i ^ 0x7fffffff);
}
__device__ __forceinline__ float dec_i(int e) {
  return __int_as_float(e >= 0 ? e : (e ^ 0x7fffffff));
}

// ---------------- K1: LayerNorm -> f16 hi/lo planes ----------------
__global__ __launch_bounds__(256)
void ln_kernel(const float* __restrict__ x, const float* __restrict__ gamma,
               const float* __restrict__ beta,
               _Float16* __restrict__ xh, _Float16* __restrict__ xl) {
  __shared__ float red[8];
  int row = blockIdx.x, t = threadIdx.x;
  const float4* xr = (const float4*)(x + (size_t)row * 1024);
  float4 v = xr[t];
  float s  = v.x + v.y + v.z + v.w;
  float s2 = v.x*v.x + v.y*v.y + v.z*v.z + v.w*v.w;
  #pragma unroll
  for (int o = 32; o >= 1; o >>= 1) {
    s  += __shfl_xor(s,  o, 64);
    s2 += __shfl_xor(s2, o, 64);
  }
  int w = t >> 6, l = t & 63;
  if (l == 0) { red[w*2] = s; red[w*2+1] = s2; }
  __syncthreads();
  float S  = red[0] + red[2] + red[4] + red[6];
  float S2 = red[1] + red[3] + red[5] + red[7];
  float mu  = S * (1.0f/1024.0f);
  float var = S2 * (1.0f/1024.0f) - mu*mu;
  float r = rsqrtf(var + LN_EPS);
  float4 g  = ((const float4*)gamma)[t];
  float4 bb = ((const float4*)beta)[t];
  float o0 = (v.x - mu) * r * g.x + bb.x;
  float o1 = (v.y - mu) * r * g.y + bb.y;
  float o2 = (v.z - mu) * r * g.z + bb.z;
  float o3 = (v.w - mu) * r * g.w + bb.w;
  HL r0 = split2(o0), r1 = split2(o1), r2 = split2(o2), r3 = split2(o3);
  half4 hh = { r0.h, r1.h, r2.h, r3.h };
  half4 ll = { r0.l, r1.l, r2.l, r3.l };
  size_t e = (size_t)row * 1024 + t*4;
  *(half4*)(xh + e) = hh;
  *(half4*)(xl + e) = ll;
}

// ---------------- K1b: weight fp32 -> f16 hi/lo planes ----------------
__global__ __launch_bounds__(256)
void cvt_kernel(const float* __restrict__ wqkv, const float* __restrict__ wout,
                _Float16* __restrict__ wqh, _Float16* __restrict__ wql,
                _Float16* __restrict__ woh, _Float16* __restrict__ wol) {
  size_t i4 = (size_t)blockIdx.x * 256 + threadIdx.x;   // float4 index, 1M total
  const float* src; _Float16 *dh, *dl; size_t off;
  if (i4 < 786432) { src = wqkv; dh = wqh; dl = wql; off = i4; }
  else             { src = wout; dh = woh; dl = wol; off = i4 - 786432; }
  float4 v = ((const float4*)src)[off];
  HL r0 = split2(v.x), r1 = split2(v.y), r2 = split2(v.z), r3 = split2(v.w);
  half4 hh = { r0.h, r1.h, r2.h, r3.h };
  half4 ll = { r0.l, r1.l, r2.l, r3.l };
  ((half4*)dh)[off] = hh;
  ((half4*)dl)[off] = ll;
}

// ---------------- K2/K5: f16-split MFMA NT GEMM, 128x128 tile ----------------
// C[m][n] = sum_k A[m][k]*B[n][k], A = Ah+Al, B = Bh+Bl (3 MFMA terms).
// MODE 0: scatter q,k -> f16 hi/lo planes [bh][n][d]; v -> fp32 [bh][n][d].
// MODE 1: CO = acc + bias (fp32).
template<int MODE>
__global__ __launch_bounds__(256)
void gemm_f16split(const _Float16* __restrict__ Ah, const _Float16* __restrict__ Al,
                   const _Float16* __restrict__ Bh, const _Float16* __restrict__ Bl,
                   const float* __restrict__ bias, float* __restrict__ CO,
                   _Float16* __restrict__ QH, _Float16* __restrict__ QL,
                   _Float16* __restrict__ KH, _Float16* __restrict__ KL,
                   float* __restrict__ CV) {
  __shared__ __align__(16) _Float16 lds[4 * 128 * 32];  // Ah | Al | Bh | Bl tiles
  const int K = 1024;
  int tid = threadIdx.x, w = tid >> 6, l = tid & 63;
  int m0 = blockIdx.y * 128, n0 = blockIdx.x * 128;
  int wm = (w >> 1) * 64, wn = (w & 1) * 64;

  const _Float16* src = (w == 0) ? Ah : (w == 1) ? Al : (w == 2) ? Bh : Bl;
  int rowbase = (w < 2) ? m0 : n0;
  _Float16* dst = lds + (size_t)w * 4096;
  int sr = l >> 2, sc = l & 3;

  float4v acc[4][4];
  #pragma unroll
  for (int u = 0; u < 4; ++u)
    #pragma unroll
    for (int vv = 0; vv < 4; ++vv) acc[u][vv] = (float4v){0.f, 0.f, 0.f, 0.f};

  int quad = l >> 4, lo16 = l & 15;
  for (int kt = 0; kt < K; kt += 32) {
    __syncthreads();
    #pragma unroll
    for (int i = 0; i < 8; ++i) {
      int row = i * 16 + sr;
      gload_lds16(src + (size_t)(rowbase + row) * K + kt + sc * 8,
                  dst + row * 32 + sc * 8);
    }
    __syncthreads();
    half8 ah[4], al[4], bh[4], bl[4];
    #pragma unroll
    for (int u = 0; u < 4; ++u) {
      int mrow = wm + u * 16 + lo16;
      int nrow = wn + u * 16 + lo16;
      ah[u] = *(const half8*)&lds[        (size_t)mrow * 32 + quad * 8];
      al[u] = *(const half8*)&lds[ 4096 + (size_t)mrow * 32 + quad * 8];
      bh[u] = *(const half8*)&lds[ 8192 + (size_t)nrow * 32 + quad * 8];
      bl[u] = *(const half8*)&lds[12288 + (size_t)nrow * 32 + quad * 8];
    }
    #pragma unroll
    for (int u = 0; u < 4; ++u)
      #pragma unroll
      for (int vv = 0; vv < 4; ++vv) {
        acc[u][vv] = mfma16(ah[u], bh[vv], acc[u][vv]);
        acc[u][vv] = mfma16(ah[u], bl[vv], acc[u][vv]);
        acc[u][vv] = mfma16(al[u], bh[vv], acc[u][vv]);
      }
  }

  // epilogue: C row = m ((lane>>4)*4+reg), col = n (lane&15)
  #pragma unroll
  for (int u = 0; u < 4; ++u) {
    #pragma unroll
    for (int vv = 0; vv < 4; ++vv) {
      #pragma unroll
      for (int rg = 0; rg < 4; ++rg) {
        int row = m0 + wm + u * 16 + quad * 4 + rg;
        int col = n0 + wn + vv * 16 + lo16;
        float val = acc[u][vv][rg];
        if (MODE == 0) {
          int which = col >> 10, h = (col >> 6) & 15, dd = col & 63;
          int b = row >> 10, i = row & 1023;
          size_t e = ((size_t)(b * 16 + h) << 16) + ((size_t)i << 6) + dd;
          if (which == 2) { CV[e] = val; }
          else {
            HL sp = split2(val);
            if (which == 0) { QH[e] = sp.h; QL[e] = sp.l; }
            else            { KH[e] = sp.h; KL[e] = sp.l; }
          }
        } else {
          CO[(size_t)row * 1024 + col] = val + bias[col];
        }
      }
    }
  }
}

// ---------------- K3 init ----------------
__global__ void init_kernel(int* minmax) {
  minmax[0] = 0x7fffffff;
  minmax[1] = (int)0x80000000;
}

// ---------------- K3: MFMA sim + top-32 select + v gather-sum ----------------
// Block = 16 q-rows of one head.  Wave w computes sim for j in
// [w*256, w*256+256) via 16x16x32 f16-split MFMA (A=q rows, B=k rows), frags
// loaded straight from global (L2-resident, coalesced 16B/lane), C-tiles
// transposed through LDS sim buffer (stride 1028 -> only 2-way conflicts).
// Then wave w selects top-32 for rows w*4..w*4+3 (ballot binary search, exact
// jax tie-break), gathers+sums v rows, global minmax via atomics.
__global__ __launch_bounds__(256)
void attn_kernel(const _Float16* __restrict__ qh, const _Float16* __restrict__ ql,
                 const _Float16* __restrict__ kh, const _Float16* __restrict__ kl,
                 const float* __restrict__ vg, float* __restrict__ xsum,
                 int* __restrict__ minmax) {
  __shared__ float simb[16][1028];   // stride 1028: 4-row quads land 2-way max
  __shared__ int sel[4][32];
  // XCD swizzle: all 64 row-blocks of a head on one XCD (k planes fit L2)
  int g = blockIdx.x;
  int xcd = g & 7, slot = g >> 3;
  int bh = (slot >> 6) * 8 + xcd, grp = slot & 63;
  int tid = threadIdx.x, w = tid >> 6, l = tid & 63;
  int quad = l >> 4, lo16 = l & 15;
  size_t hb = (size_t)bh << 16;

  // A-frags: q rows grp*16..+15 (shared by all 4 waves; L1 broadcast)
  const _Float16* qhp = qh + hb + ((size_t)(grp * 16 + lo16) << 6);
  const _Float16* qlp = ql + hb + ((size_t)(grp * 16 + lo16) << 6);
  half8 ah0 = *(const half8*)(qhp + quad * 8);
  half8 ah1 = *(const half8*)(qhp + 32 + quad * 8);
  half8 al0 = *(const half8*)(qlp + quad * 8);
  half8 al1 = *(const half8*)(qlp + 32 + quad * 8);

  const _Float16* khp = kh + hb;
  const _Float16* klp = kl + hb;
  int jbase = w * 256;

  // double-buffered B-frag loads (4 x 16B per j-tile)
  half8 b0, b1, c0, c1, d0, d1, e0, e1;
  {
    size_t off = ((size_t)(jbase + lo16) << 6) + quad * 8;
    b0 = *(const half8*)(khp + off);
    b1 = *(const half8*)(khp + off + 32);
    c0 = *(const half8*)(klp + off);
    c1 = *(const half8*)(klp + off + 32);
  }
  #pragma unroll
  for (int tt = 0; tt < 16; ++tt) {
    if (tt + 1 < 16) {
      size_t off = ((size_t)(jbase + (tt + 1) * 16 + lo16) << 6) + quad * 8;
      d0 = *(const half8*)(khp + off);
      d1 = *(const half8*)(khp + off + 32);
      e0 = *(const half8*)(klp + off);
      e1 = *(const half8*)(klp + off + 32);
    }
    float4v acc = (float4v){0.f, 0.f, 0.f, 0.f};
    acc = mfma16(ah0, b0, acc);
    acc = mfma16(ah0, c0, acc);
    acc = mfma16(al0, b0, acc);
    acc = mfma16(ah1, b1, acc);
    acc = mfma16(ah1, c1, acc);
    acc = mfma16(al1, b1, acc);
    int jc = jbase + tt * 16 + lo16;
    #pragma unroll
    for (int rg = 0; rg < 4; ++rg)
      simb[quad * 4 + rg][jc] = acc[rg];
    b0 = d0; b1 = d1; c0 = e0; c1 = e1;
  }
  __syncthreads();

  float mn = 3.4e38f, mx = -3.4e38f;
  const float* vb = vg + hb;
  unsigned long long below = (1ull << l) - 1ull;

  #pragma unroll
  for (int r = 0; r < 4; ++r) {
    int row = w * 4 + r;
    unsigned ku[16];
    #pragma unroll
    for (int s = 0; s < 16; ++s) ku[s] = fkey(simb[row][s * 64 + l]);

    // binary search for 32nd-largest key; early exit at exact count 32
    unsigned cur = 0u;
    bool exact = false;
    for (int bit = 31; bit >= 0; --bit) {
      unsigned T = cur | (1u << bit);
      int c = 0;
      #pragma unroll
      for (int s = 0; s < 16; ++s) c += __popcll(__ballot(ku[s] >= T));
      if (c >= 32) {
        cur = T;
        if (c == 32) { exact = true; break; }
      }
    }
    int need = 9999;
    if (!exact) {
      int gcnt = 0;
      #pragma unroll
      for (int s = 0; s < 16; ++s) gcnt += __popcll(__ballot(ku[s] > cur));
      need = 32 - gcnt;   // ties taken lowest-j first (jax tie-break)
    }

    int base = 0, eqb = 0;
    #pragma unroll
    for (int s = 0; s < 16; ++s) {
      bool gt = ku[s] > cur;
      bool eq = ku[s] == cur;
      unsigned long long meq = __ballot(eq);
      int eqr = eqb + __popcll(meq & below);
      bool take = gt || (eq && (eqr < need));
      unsigned long long mtk = __ballot(take);
      if (take) sel[w][base + __popcll(mtk & below)] = s * 64 + l;
      base += __popcll(mtk);
      eqb  += __popcll(meq);
    }

    float acc = 0.0f;
    #pragma unroll
    for (int s2 = 0; s2 < 32; ++s2) {
      int j = sel[w][s2];
      acc += vb[((size_t)j << 6) + l];
    }
    xsum[hb + ((size_t)(grp * 16 + row) << 6) + l] = acc;
    mn = fminf(mn, acc);
    mx = fmaxf(mx, acc);
  }

  #pragma unroll
  for (int o = 32; o >= 1; o >>= 1) {
    mn = fminf(mn, __shfl_xor(mn, o, 64));
    mx = fmaxf(mx, __shfl_xor(mx, o, 64));
  }
  if (l == 0) {
    atomicMin(minmax,     enc_i(mn));
    atomicMax(minmax + 1, enc_i(mx));
  }
}

// ---------------- K4: minmax-norm + exp + transpose -> f16 hi/lo ----------------
__global__ __launch_bounds__(256)
void fin_kernel(const float* __restrict__ xsum, const int* __restrict__ minmax,
                _Float16* __restrict__ oh, _Float16* __restrict__ ol) {
  int idx = blockIdx.x * 256 + threadIdx.x;  // float4 index
  float mn = dec_i(minmax[0]);
  float mx = dec_i(minmax[1]);
  float inv = 1.0f / (mx - mn);
  float4 xv = ((const float4*)xsum)[idx];
  float o0 = expf((xv.x - mn) * inv);
  float o1 = expf((xv.y - mn) * inv);
  float o2 = expf((xv.z - mn) * inv);
  float o3 = expf((xv.w - mn) * inv);
  HL r0 = split2(o0), r1 = split2(o1), r2 = split2(o2), r3 = split2(o3);
  half4 hh = { r0.h, r1.h, r2.h, r3.h };
  half4 ll = { r0.l, r1.l, r2.l, r3.l };
  int e0 = idx << 2;
  int bh = e0 >> 16, i = (e0 >> 6) & 1023, dd = e0 & 63;
  int b = bh >> 4, h = bh & 15;
  size_t oe = ((size_t)(b * 1024 + i) << 10) + (h << 6) + dd;
  *(half4*)(oh + oe) = hh;
  *(half4*)(ol + oe) = ll;
}

// ---------------- launch ----------------
extern "C" void kernel_launch(void* const* d_in, const int* in_sizes, int n_in,
                              void* d_out, int out_size, void* d_ws, size_t ws_size,
                              hipStream_t stream) {
  const float* x     = (const float*)d_in[0];
  const float* gamma = (const float*)d_in[1];
  const float* beta  = (const float*)d_in[2];
  const float* w_qkv = (const float*)d_in[3];
  const float* w_out = (const float*)d_in[4];
  const float* b_out = (const float*)d_in[5];

  char* B = (char*)d_ws;
  const size_t MB = 1024ull * 1024ull;
  float*    v   = (float*)B;                        // 16 MB [bh][n][d]
  _Float16* qh  = (_Float16*)(B + 16*MB);           // 8 MB each plane
  _Float16* ql  = (_Float16*)(B + 24*MB);
  _Float16* kh  = (_Float16*)(B + 32*MB);
  _Float16* kl  = (_Float16*)(B + 40*MB);
  float*    xs  = (float*)(B + 48*MB);              // 16 MB (attn output)
  _Float16* xh  = (_Float16*)(B + 48*MB);           // LN planes (dead before xs)
  _Float16* xl  = (_Float16*)(B + 56*MB);
  _Float16* wqh = (_Float16*)(B + 64*MB);           // 6 MB
  _Float16* wql = (_Float16*)(B + 70*MB);
  _Float16* woh = (_Float16*)(B + 76*MB);           // 2 MB
  _Float16* wol = (_Float16*)(B + 78*MB);
  int*   minmax = (int*)(B + 80*MB);
  _Float16* oth = qh;                               // reuse q planes after attn
  _Float16* otl = ql;

  ln_kernel<<<4096, 256, 0, stream>>>(x, gamma, beta, xh, xl);
  cvt_kernel<<<4096, 256, 0, stream>>>(w_qkv, w_out, wqh, wql, woh, wol);
  gemm_f16split<0><<<dim3(24, 32), 256, 0, stream>>>(
      xh, xl, wqh, wql, nullptr, nullptr, qh, ql, kh, kl, v);
  init_kernel<<<1, 1, 0, stream>>>(minmax);
  attn_kernel<<<4096, 256, 0, stream>>>(qh, ql, kh, kl, v, xs, minmax);
  fin_kernel<<<4096, 256, 0, stream>>>(xs, minmax, oth, otl);
  gemm_f16split<1><<<dim3(8, 32), 256, 0, stream>>>(
      oth, otl, woh, wol, b_out, (float*)d_out,
      nullptr, nullptr, nullptr, nullptr, nullptr);
}

// Round 7
// 532.666 us; speedup vs baseline: 1.3272x; 1.3272x over previous
//
#include <hip/hip_runtime.h>

// ProdAttention: LN -> QKV proj -> per-head top-32 of q.k^T (softmax monotone
// => select on raw sim) -> unweighted gather-sum of selected v rows -> global
// minmax-normalize + exp -> transpose -> output proj + bias.
// All GEMM-shaped compute on MFMA with f16 hi/lo split (3 terms ~ fp32).
// R7 change: NO per-wave global atomics in attn (they serialized ~32K ops on
// two cache lines -> the ~480us floor of rounds 3-5).  Global min/max now via
// a separate 256-block reduce over xsum.

#define LN_EPS 1e-5f

using half8   = __attribute__((ext_vector_type(8))) _Float16;
using half4   = __attribute__((ext_vector_type(4))) _Float16;
using float4v = __attribute__((ext_vector_type(4))) float;

__device__ __forceinline__ void gload_lds16(const void* g, void* l) {
  __builtin_amdgcn_global_load_lds(
      (const __attribute__((address_space(1))) void*)g,
      (__attribute__((address_space(3))) void*)l, 16, 0, 0);
}
__device__ __forceinline__ float4v mfma16(half8 a, half8 b, float4v c) {
  return __builtin_amdgcn_mfma_f32_16x16x32_f16(a, b, c, 0, 0, 0);
}
struct HL { _Float16 h, l; };
__device__ __forceinline__ HL split2(float x) {
  _Float16 h = (_Float16)x;
  return { h, (_Float16)(x - (float)h) };
}

// ---------------- order-preserving key helpers ----------------
__device__ __forceinline__ unsigned fkey(float f) {
  unsigned u = __float_as_uint(f);
  return ((int)u < 0) ? ~u : (u | 0x80000000u);
}
__device__ __forceinline__ int enc_i(float f) {
  int i = __float_as_int(f);
  return i >= 0 ? i : (i ^ 0x7fffffff);
}
__device__ __forceinline__ float dec_i(int e) {
  return __int_as_float(e >= 0 ? e : (e ^ 0x7fffffff));
}

// ---------------- K1: LayerNorm -> f16 hi/lo planes ----------------
__global__ __launch_bounds__(256)
void ln_kernel(const float* __restrict__ x, const float* __restrict__ gamma,
               const float* __restrict__ beta,
               _Float16* __restrict__ xh, _Float16* __restrict__ xl) {
  __shared__ float red[8];
  int row = blockIdx.x, t = threadIdx.x;
  const float4* xr = (const float4*)(x + (size_t)row * 1024);
  float4 v = xr[t];
  float s  = v.x + v.y + v.z + v.w;
  float s2 = v.x*v.x + v.y*v.y + v.z*v.z + v.w*v.w;
  #pragma unroll
  for (int o = 32; o >= 1; o >>= 1) {
    s  += __shfl_xor(s,  o, 64);
    s2 += __shfl_xor(s2, o, 64);
  }
  int w = t >> 6, l = t & 63;
  if (l == 0) { red[w*2] = s; red[w*2+1] = s2; }
  __syncthreads();
  float S  = red[0] + red[2] + red[4] + red[6];
  float S2 = red[1] + red[3] + red[5] + red[7];
  float mu  = S * (1.0f/1024.0f);
  float var = S2 * (1.0f/1024.0f) - mu*mu;
  float r = rsqrtf(var + LN_EPS);
  float4 g  = ((const float4*)gamma)[t];
  float4 bb = ((const float4*)beta)[t];
  float o0 = (v.x - mu) * r * g.x + bb.x;
  float o1 = (v.y - mu) * r * g.y + bb.y;
  float o2 = (v.z - mu) * r * g.z + bb.z;
  float o3 = (v.w - mu) * r * g.w + bb.w;
  HL r0 = split2(o0), r1 = split2(o1), r2 = split2(o2), r3 = split2(o3);
  half4 hh = { r0.h, r1.h, r2.h, r3.h };
  half4 ll = { r0.l, r1.l, r2.l, r3.l };
  size_t e = (size_t)row * 1024 + t*4;
  *(half4*)(xh + e) = hh;
  *(half4*)(xl + e) = ll;
}

// ---------------- K1b: weight fp32 -> f16 hi/lo planes ----------------
__global__ __launch_bounds__(256)
void cvt_kernel(const float* __restrict__ wqkv, const float* __restrict__ wout,
                _Float16* __restrict__ wqh, _Float16* __restrict__ wql,
                _Float16* __restrict__ woh, _Float16* __restrict__ wol) {
  size_t i4 = (size_t)blockIdx.x * 256 + threadIdx.x;   // float4 index, 1M total
  const float* src; _Float16 *dh, *dl; size_t off;
  if (i4 < 786432) { src = wqkv; dh = wqh; dl = wql; off = i4; }
  else             { src = wout; dh = woh; dl = wol; off = i4 - 786432; }
  float4 v = ((const float4*)src)[off];
  HL r0 = split2(v.x), r1 = split2(v.y), r2 = split2(v.z), r3 = split2(v.w);
  half4 hh = { r0.h, r1.h, r2.h, r3.h };
  half4 ll = { r0.l, r1.l, r2.l, r3.l };
  ((half4*)dh)[off] = hh;
  ((half4*)dl)[off] = ll;
}

// ---------------- K2/K7: f16-split MFMA NT GEMM, 128x128 tile ----------------
// C[m][n] = sum_k A[m][k]*B[n][k], A = Ah+Al, B = Bh+Bl (3 MFMA terms).
// MODE 0: scatter q,k -> f16 hi/lo planes [bh][n][d]; v -> fp32 [bh][n][d].
// MODE 1: CO = acc + bias (fp32).
template<int MODE>
__global__ __launch_bounds__(256)
void gemm_f16split(const _Float16* __restrict__ Ah, const _Float16* __restrict__ Al,
                   const _Float16* __restrict__ Bh, const _Float16* __restrict__ Bl,
                   const float* __restrict__ bias, float* __restrict__ CO,
                   _Float16* __restrict__ QH, _Float16* __restrict__ QL,
                   _Float16* __restrict__ KH, _Float16* __restrict__ KL,
                   float* __restrict__ CV) {
  __shared__ __align__(16) _Float16 lds[4 * 128 * 32];  // Ah | Al | Bh | Bl tiles
  const int K = 1024;
  int tid = threadIdx.x, w = tid >> 6, l = tid & 63;
  int m0 = blockIdx.y * 128, n0 = blockIdx.x * 128;
  int wm = (w >> 1) * 64, wn = (w & 1) * 64;

  const _Float16* src = (w == 0) ? Ah : (w == 1) ? Al : (w == 2) ? Bh : Bl;
  int rowbase = (w < 2) ? m0 : n0;
  _Float16* dst = lds + (size_t)w * 4096;
  int sr = l >> 2, sc = l & 3;

  float4v acc[4][4];
  #pragma unroll
  for (int u = 0; u < 4; ++u)
    #pragma unroll
    for (int vv = 0; vv < 4; ++vv) acc[u][vv] = (float4v){0.f, 0.f, 0.f, 0.f};

  int quad = l >> 4, lo16 = l & 15;
  for (int kt = 0; kt < K; kt += 32) {
    __syncthreads();
    #pragma unroll
    for (int i = 0; i < 8; ++i) {
      int row = i * 16 + sr;
      gload_lds16(src + (size_t)(rowbase + row) * K + kt + sc * 8,
                  dst + row * 32 + sc * 8);
    }
    __syncthreads();
    half8 ah[4], al[4], bh[4], bl[4];
    #pragma unroll
    for (int u = 0; u < 4; ++u) {
      int mrow = wm + u * 16 + lo16;
      int nrow = wn + u * 16 + lo16;
      ah[u] = *(const half8*)&lds[        (size_t)mrow * 32 + quad * 8];
      al[u] = *(const half8*)&lds[ 4096 + (size_t)mrow * 32 + quad * 8];
      bh[u] = *(const half8*)&lds[ 8192 + (size_t)nrow * 32 + quad * 8];
      bl[u] = *(const half8*)&lds[12288 + (size_t)nrow * 32 + quad * 8];
    }
    #pragma unroll
    for (int u = 0; u < 4; ++u)
      #pragma unroll
      for (int vv = 0; vv < 4; ++vv) {
        acc[u][vv] = mfma16(ah[u], bh[vv], acc[u][vv]);
        acc[u][vv] = mfma16(ah[u], bl[vv], acc[u][vv]);
        acc[u][vv] = mfma16(al[u], bh[vv], acc[u][vv]);
      }
  }

  // epilogue: C row = m ((lane>>4)*4+reg), col = n (lane&15)
  #pragma unroll
  for (int u = 0; u < 4; ++u) {
    #pragma unroll
    for (int vv = 0; vv < 4; ++vv) {
      #pragma unroll
      for (int rg = 0; rg < 4; ++rg) {
        int row = m0 + wm + u * 16 + quad * 4 + rg;
        int col = n0 + wn + vv * 16 + lo16;
        float val = acc[u][vv][rg];
        if (MODE == 0) {
          int which = col >> 10, h = (col >> 6) & 15, dd = col & 63;
          int b = row >> 10, i = row & 1023;
          size_t e = ((size_t)(b * 16 + h) << 16) + ((size_t)i << 6) + dd;
          if (which == 2) { CV[e] = val; }
          else {
            HL sp = split2(val);
            if (which == 0) { QH[e] = sp.h; QL[e] = sp.l; }
            else            { KH[e] = sp.h; KL[e] = sp.l; }
          }
        } else {
          CO[(size_t)row * 1024 + col] = val + bias[col];
        }
      }
    }
  }
}

// ---------------- K3 init ----------------
__global__ void init_kernel(int* minmax) {
  minmax[0] = 0x7fffffff;
  minmax[1] = (int)0x80000000;
}

// ---------------- K4: MFMA sim + top-32 select + v gather-sum ----------------
// Identical to round 5 EXCEPT: no global min/max atomics (they serialized
// 32K same-line ops -> suspected ~480us floor).  minmax moved to reduce_kernel.
__global__ __launch_bounds__(256)
void attn_kernel(const _Float16* __restrict__ qh, const _Float16* __restrict__ ql,
                 const _Float16* __restrict__ kh, const _Float16* __restrict__ kl,
                 const float* __restrict__ vg, float* __restrict__ xsum) {
  __shared__ float simb[16][1028];   // stride 1028: 4-row quads land 2-way max
  __shared__ int sel[4][32];
  // XCD swizzle: all 64 row-blocks of a head on one XCD (k planes fit L2)
  int g = blockIdx.x;
  int xcd = g & 7, slot = g >> 3;
  int bh = (slot >> 6) * 8 + xcd, grp = slot & 63;
  int tid = threadIdx.x, w = tid >> 6, l = tid & 63;
  int quad = l >> 4, lo16 = l & 15;
  size_t hb = (size_t)bh << 16;

  // A-frags: q rows grp*16..+15 (shared by all 4 waves; L1 broadcast)
  const _Float16* qhp = qh + hb + ((size_t)(grp * 16 + lo16) << 6);
  const _Float16* qlp = ql + hb + ((size_t)(grp * 16 + lo16) << 6);
  half8 ah0 = *(const half8*)(qhp + quad * 8);
  half8 ah1 = *(const half8*)(qhp + 32 + quad * 8);
  half8 al0 = *(const half8*)(qlp + quad * 8);
  half8 al1 = *(const half8*)(qlp + 32 + quad * 8);

  const _Float16* khp = kh + hb;
  const _Float16* klp = kl + hb;
  int jbase = w * 256;

  // double-buffered B-frag loads (4 x 16B per j-tile)
  half8 b0, b1, c0, c1, d0, d1, e0, e1;
  {
    size_t off = ((size_t)(jbase + lo16) << 6) + quad * 8;
    b0 = *(const half8*)(khp + off);
    b1 = *(const half8*)(khp + off + 32);
    c0 = *(const half8*)(klp + off);
    c1 = *(const half8*)(klp + off + 32);
  }
  #pragma unroll
  for (int tt = 0; tt < 16; ++tt) {
    if (tt + 1 < 16) {
      size_t off = ((size_t)(jbase + (tt + 1) * 16 + lo16) << 6) + quad * 8;
      d0 = *(const half8*)(khp + off);
      d1 = *(const half8*)(khp + off + 32);
      e0 = *(const half8*)(klp + off);
      e1 = *(const half8*)(klp + off + 32);
    }
    float4v acc = (float4v){0.f, 0.f, 0.f, 0.f};
    acc = mfma16(ah0, b0, acc);
    acc = mfma16(ah0, c0, acc);
    acc = mfma16(al0, b0, acc);
    acc = mfma16(ah1, b1, acc);
    acc = mfma16(ah1, c1, acc);
    acc = mfma16(al1, b1, acc);
    int jc = jbase + tt * 16 + lo16;
    #pragma unroll
    for (int rg = 0; rg < 4; ++rg)
      simb[quad * 4 + rg][jc] = acc[rg];
    b0 = d0; b1 = d1; c0 = e0; c1 = e1;
  }
  __syncthreads();

  const float* vb = vg + hb;
  unsigned long long below = (1ull << l) - 1ull;

  #pragma unroll
  for (int r = 0; r < 4; ++r) {
    int row = w * 4 + r;
    unsigned ku[16];
    #pragma unroll
    for (int s = 0; s < 16; ++s) ku[s] = fkey(simb[row][s * 64 + l]);

    // binary search for 32nd-largest key; early exit at exact count 32
    unsigned cur = 0u;
    bool exact = false;
    for (int bit = 31; bit >= 0; --bit) {
      unsigned T = cur | (1u << bit);
      int c = 0;
      #pragma unroll
      for (int s = 0; s < 16; ++s) c += __popcll(__ballot(ku[s] >= T));
      if (c >= 32) {
        cur = T;
        if (c == 32) { exact = true; break; }
      }
    }
    int need = 9999;
    if (!exact) {
      int gcnt = 0;
      #pragma unroll
      for (int s = 0; s < 16; ++s) gcnt += __popcll(__ballot(ku[s] > cur));
      need = 32 - gcnt;   // ties taken lowest-j first (jax tie-break)
    }

    int base = 0, eqb = 0;
    #pragma unroll
    for (int s = 0; s < 16; ++s) {
      bool gt = ku[s] > cur;
      bool eq = ku[s] == cur;
      unsigned long long meq = __ballot(eq);
      int eqr = eqb + __popcll(meq & below);
      bool take = gt || (eq && (eqr < need));
      unsigned long long mtk = __ballot(take);
      if (take) sel[w][base + __popcll(mtk & below)] = s * 64 + l;
      base += __popcll(mtk);
      eqb  += __popcll(meq);
    }

    float acc = 0.0f;
    #pragma unroll
    for (int s2 = 0; s2 < 32; ++s2) {
      int j = sel[w][s2];
      acc += vb[((size_t)j << 6) + l];
    }
    xsum[hb + ((size_t)(grp * 16 + row) << 6) + l] = acc;
  }
}

// ---------------- K5: global min/max reduce over xsum (256 blocks) ----------
__global__ __launch_bounds__(256)
void reduce_kernel(const float* __restrict__ xsum, int* __restrict__ minmax) {
  __shared__ float red[8];
  int tid = threadIdx.x, w = tid >> 6, l = tid & 63;
  const float4* p = (const float4*)xsum + (size_t)blockIdx.x * 4096 + tid;
  float mn = 3.4e38f, mx = -3.4e38f;
  #pragma unroll
  for (int i = 0; i < 16; ++i) {
    float4 v = p[(size_t)i * 256];
    mn = fminf(mn, fminf(fminf(v.x, v.y), fminf(v.z, v.w)));
    mx = fmaxf(mx, fmaxf(fmaxf(v.x, v.y), fmaxf(v.z, v.w)));
  }
  #pragma unroll
  for (int o = 32; o >= 1; o >>= 1) {
    mn = fminf(mn, __shfl_xor(mn, o, 64));
    mx = fmaxf(mx, __shfl_xor(mx, o, 64));
  }
  if (l == 0) { red[w*2] = mn; red[w*2+1] = mx; }
  __syncthreads();
  if (tid == 0) {
    mn = fminf(fminf(red[0], red[2]), fminf(red[4], red[6]));
    mx = fmaxf(fmaxf(red[1], red[3]), fmaxf(red[5], red[7]));
    atomicMin(minmax,     enc_i(mn));
    atomicMax(minmax + 1, enc_i(mx));
  }
}

// ---------------- K6: minmax-norm + exp + transpose -> f16 hi/lo ------------
__global__ __launch_bounds__(256)
void fin_kernel(const float* __restrict__ xsum, const int* __restrict__ minmax,
                _Float16* __restrict__ oh, _Float16* __restrict__ ol) {
  int idx = blockIdx.x * 256 + threadIdx.x;  // float4 index
  float mn = dec_i(minmax[0]);
  float mx = dec_i(minmax[1]);
  float inv = 1.0f / (mx - mn);
  float4 xv = ((const float4*)xsum)[idx];
  float o0 = expf((xv.x - mn) * inv);
  float o1 = expf((xv.y - mn) * inv);
  float o2 = expf((xv.z - mn) * inv);
  float o3 = expf((xv.w - mn) * inv);
  HL r0 = split2(o0), r1 = split2(o1), r2 = split2(o2), r3 = split2(o3);
  half4 hh = { r0.h, r1.h, r2.h, r3.h };
  half4 ll = { r0.l, r1.l, r2.l, r3.l };
  int e0 = idx << 2;
  int bh = e0 >> 16, i = (e0 >> 6) & 1023, dd = e0 & 63;
  int b = bh >> 4, h = bh & 15;
  size_t oe = ((size_t)(b * 1024 + i) << 10) + (h << 6) + dd;
  *(half4*)(oh + oe) = hh;
  *(half4*)(ol + oe) = ll;
}

// ---------------- launch ----------------
extern "C" void kernel_launch(void* const* d_in, const int* in_sizes, int n_in,
                              void* d_out, int out_size, void* d_ws, size_t ws_size,
                              hipStream_t stream) {
  const float* x     = (const float*)d_in[0];
  const float* gamma = (const float*)d_in[1];
  const float* beta  = (const float*)d_in[2];
  const float* w_qkv = (const float*)d_in[3];
  const float* w_out = (const float*)d_in[4];
  const float* b_out = (const float*)d_in[5];

  char* B = (char*)d_ws;
  const size_t MB = 1024ull * 1024ull;
  float*    v   = (float*)B;                        // 16 MB [bh][n][d]
  _Float16* qh  = (_Float16*)(B + 16*MB);           // 8 MB each plane
  _Float16* ql  = (_Float16*)(B + 24*MB);
  _Float16* kh  = (_Float16*)(B + 32*MB);
  _Float16* kl  = (_Float16*)(B + 40*MB);
  float*    xs  = (float*)(B + 48*MB);              // 16 MB (attn output)
  _Float16* xh  = (_Float16*)(B + 48*MB);           // LN planes (dead before xs)
  _Float16* xl  = (_Float16*)(B + 56*MB);
  _Float16* wqh = (_Float16*)(B + 64*MB);           // 6 MB
  _Float16* wql = (_Float16*)(B + 70*MB);
  _Float16* woh = (_Float16*)(B + 76*MB);           // 2 MB
  _Float16* wol = (_Float16*)(B + 78*MB);
  int*   minmax = (int*)(B + 80*MB);
  _Float16* oth = qh;                               // reuse q planes after attn
  _Float16* otl = ql;

  ln_kernel<<<4096, 256, 0, stream>>>(x, gamma, beta, xh, xl);
  cvt_kernel<<<4096, 256, 0, stream>>>(w_qkv, w_out, wqh, wql, woh, wol);
  gemm_f16split<0><<<dim3(24, 32), 256, 0, stream>>>(
      xh, xl, wqh, wql, nullptr, nullptr, qh, ql, kh, kl, v);
  init_kernel<<<1, 1, 0, stream>>>(minmax);
  attn_kernel<<<4096, 256, 0, stream>>>(qh, ql, kh, kl, v, xs);
  reduce_kernel<<<256, 256, 0, stream>>>(xs, minmax);
  fin_kernel<<<4096, 256, 0, stream>>>(xs, minmax, oth, otl);
  gemm_f16split<1><<<dim3(8, 32), 256, 0, stream>>>(
      oth, otl, woh, wol, b_out, (float*)d_out,
      nullptr, nullptr, nullptr, nullptr, nullptr);
}

// Round 8
// 497.412 us; speedup vs baseline: 1.4213x; 1.0709x over previous
//
#include <hip/hip_runtime.h>

// ProdAttention: LN -> QKV proj -> per-head top-32 of q.k^T (softmax monotone
// => select on raw sim) -> unweighted gather-sum of selected v rows -> global
// minmax-normalize + exp -> transpose -> output proj + bias.
// GEMM-shaped compute on MFMA with f16 hi/lo split (3 terms ~ fp32).
// R8: attn split into sim GEMM (throughput) -> global sim scratch (chunked to
// fit ws_size) -> select kernel (1 row/wave, no big LDS, high occupancy).
// R7 showed fused attn is latency-bound at 22% occupancy (66KB LDS).

#define LN_EPS 1e-5f

using half8   = __attribute__((ext_vector_type(8))) _Float16;
using half4   = __attribute__((ext_vector_type(4))) _Float16;
using float4v = __attribute__((ext_vector_type(4))) float;

__device__ __forceinline__ void gload_lds16(const void* g, void* l) {
  __builtin_amdgcn_global_load_lds(
      (const __attribute__((address_space(1))) void*)g,
      (__attribute__((address_space(3))) void*)l, 16, 0, 0);
}
__device__ __forceinline__ float4v mfma16(half8 a, half8 b, float4v c) {
  return __builtin_amdgcn_mfma_f32_16x16x32_f16(a, b, c, 0, 0, 0);
}
struct HL { _Float16 h, l; };
__device__ __forceinline__ HL split2(float x) {
  _Float16 h = (_Float16)x;
  return { h, (_Float16)(x - (float)h) };
}

// ---------------- order-preserving key helpers ----------------
__device__ __forceinline__ unsigned fkey(float f) {
  unsigned u = __float_as_uint(f);
  return ((int)u < 0) ? ~u : (u | 0x80000000u);
}
__device__ __forceinline__ int enc_i(float f) {
  int i = __float_as_int(f);
  return i >= 0 ? i : (i ^ 0x7fffffff);
}
__device__ __forceinline__ float dec_i(int e) {
  return __int_as_float(e >= 0 ? e : (e ^ 0x7fffffff));
}

// ---------------- K1: LayerNorm -> f16 hi/lo planes ----------------
__global__ __launch_bounds__(256)
void ln_kernel(const float* __restrict__ x, const float* __restrict__ gamma,
               const float* __restrict__ beta,
               _Float16* __restrict__ xh, _Float16* __restrict__ xl) {
  __shared__ float red[8];
  int row = blockIdx.x, t = threadIdx.x;
  const float4* xr = (const float4*)(x + (size_t)row * 1024);
  float4 v = xr[t];
  float s  = v.x + v.y + v.z + v.w;
  float s2 = v.x*v.x + v.y*v.y + v.z*v.z + v.w*v.w;
  #pragma unroll
  for (int o = 32; o >= 1; o >>= 1) {
    s  += __shfl_xor(s,  o, 64);
    s2 += __shfl_xor(s2, o, 64);
  }
  int w = t >> 6, l = t & 63;
  if (l == 0) { red[w*2] = s; red[w*2+1] = s2; }
  __syncthreads();
  float S  = red[0] + red[2] + red[4] + red[6];
  float S2 = red[1] + red[3] + red[5] + red[7];
  float mu  = S * (1.0f/1024.0f);
  float var = S2 * (1.0f/1024.0f) - mu*mu;
  float r = rsqrtf(var + LN_EPS);
  float4 g  = ((const float4*)gamma)[t];
  float4 bb = ((const float4*)beta)[t];
  float o0 = (v.x - mu) * r * g.x + bb.x;
  float o1 = (v.y - mu) * r * g.y + bb.y;
  float o2 = (v.z - mu) * r * g.z + bb.z;
  float o3 = (v.w - mu) * r * g.w + bb.w;
  HL r0 = split2(o0), r1 = split2(o1), r2 = split2(o2), r3 = split2(o3);
  half4 hh = { r0.h, r1.h, r2.h, r3.h };
  half4 ll = { r0.l, r1.l, r2.l, r3.l };
  size_t e = (size_t)row * 1024 + t*4;
  *(half4*)(xh + e) = hh;
  *(half4*)(xl + e) = ll;
}

// ---------------- K1b: weight fp32 -> f16 hi/lo planes ----------------
__global__ __launch_bounds__(256)
void cvt_kernel(const float* __restrict__ wqkv, const float* __restrict__ wout,
                _Float16* __restrict__ wqh, _Float16* __restrict__ wql,
                _Float16* __restrict__ woh, _Float16* __restrict__ wol) {
  size_t i4 = (size_t)blockIdx.x * 256 + threadIdx.x;   // float4 index, 1M total
  const float* src; _Float16 *dh, *dl; size_t off;
  if (i4 < 786432) { src = wqkv; dh = wqh; dl = wql; off = i4; }
  else             { src = wout; dh = woh; dl = wol; off = i4 - 786432; }
  float4 v = ((const float4*)src)[off];
  HL r0 = split2(v.x), r1 = split2(v.y), r2 = split2(v.z), r3 = split2(v.w);
  half4 hh = { r0.h, r1.h, r2.h, r3.h };
  half4 ll = { r0.l, r1.l, r2.l, r3.l };
  ((half4*)dh)[off] = hh;
  ((half4*)dl)[off] = ll;
}

// ---------------- K2/K7: f16-split MFMA NT GEMM, 128x128 tile ----------------
// C[m][n] = sum_k A[m][k]*B[n][k], A = Ah+Al, B = Bh+Bl (3 MFMA terms).
// MODE 0: scatter q,k -> f16 hi/lo planes [bh][n][d]; v -> fp32 [bh][n][d].
// MODE 1: CO = acc + bias (fp32).
template<int MODE>
__global__ __launch_bounds__(256)
void gemm_f16split(const _Float16* __restrict__ Ah, const _Float16* __restrict__ Al,
                   const _Float16* __restrict__ Bh, const _Float16* __restrict__ Bl,
                   const float* __restrict__ bias, float* __restrict__ CO,
                   _Float16* __restrict__ QH, _Float16* __restrict__ QL,
                   _Float16* __restrict__ KH, _Float16* __restrict__ KL,
                   float* __restrict__ CV) {
  __shared__ __align__(16) _Float16 lds[4 * 128 * 32];  // Ah | Al | Bh | Bl tiles
  const int K = 1024;
  int tid = threadIdx.x, w = tid >> 6, l = tid & 63;
  int m0 = blockIdx.y * 128, n0 = blockIdx.x * 128;
  int wm = (w >> 1) * 64, wn = (w & 1) * 64;

  const _Float16* src = (w == 0) ? Ah : (w == 1) ? Al : (w == 2) ? Bh : Bl;
  int rowbase = (w < 2) ? m0 : n0;
  _Float16* dst = lds + (size_t)w * 4096;
  int sr = l >> 2, sc = l & 3;

  float4v acc[4][4];
  #pragma unroll
  for (int u = 0; u < 4; ++u)
    #pragma unroll
    for (int vv = 0; vv < 4; ++vv) acc[u][vv] = (float4v){0.f, 0.f, 0.f, 0.f};

  int quad = l >> 4, lo16 = l & 15;
  for (int kt = 0; kt < K; kt += 32) {
    __syncthreads();
    #pragma unroll
    for (int i = 0; i < 8; ++i) {
      int row = i * 16 + sr;
      gload_lds16(src + (size_t)(rowbase + row) * K + kt + sc * 8,
                  dst + row * 32 + sc * 8);
    }
    __syncthreads();
    half8 ah[4], al[4], bh[4], bl[4];
    #pragma unroll
    for (int u = 0; u < 4; ++u) {
      int mrow = wm + u * 16 + lo16;
      int nrow = wn + u * 16 + lo16;
      ah[u] = *(const half8*)&lds[        (size_t)mrow * 32 + quad * 8];
      al[u] = *(const half8*)&lds[ 4096 + (size_t)mrow * 32 + quad * 8];
      bh[u] = *(const half8*)&lds[ 8192 + (size_t)nrow * 32 + quad * 8];
      bl[u] = *(const half8*)&lds[12288 + (size_t)nrow * 32 + quad * 8];
    }
    #pragma unroll
    for (int u = 0; u < 4; ++u)
      #pragma unroll
      for (int vv = 0; vv < 4; ++vv) {
        acc[u][vv] = mfma16(ah[u], bh[vv], acc[u][vv]);
        acc[u][vv] = mfma16(ah[u], bl[vv], acc[u][vv]);
        acc[u][vv] = mfma16(al[u], bh[vv], acc[u][vv]);
      }
  }

  // epilogue: C row = m ((lane>>4)*4+reg), col = n (lane&15)
  #pragma unroll
  for (int u = 0; u < 4; ++u) {
    #pragma unroll
    for (int vv = 0; vv < 4; ++vv) {
      #pragma unroll
      for (int rg = 0; rg < 4; ++rg) {
        int row = m0 + wm + u * 16 + quad * 4 + rg;
        int col = n0 + wn + vv * 16 + lo16;
        float val = acc[u][vv][rg];
        if (MODE == 0) {
          int which = col >> 10, h = (col >> 6) & 15, dd = col & 63;
          int b = row >> 10, i = row & 1023;
          size_t e = ((size_t)(b * 16 + h) << 16) + ((size_t)i << 6) + dd;
          if (which == 2) { CV[e] = val; }
          else {
            HL sp = split2(val);
            if (which == 0) { QH[e] = sp.h; QL[e] = sp.l; }
            else            { KH[e] = sp.h; KL[e] = sp.l; }
          }
        } else {
          CO[(size_t)row * 1024 + col] = val + bias[col];
        }
      }
    }
  }
}

// ---------------- K3 init ----------------
__global__ void init_kernel(int* minmax) {
  minmax[0] = 0x7fffffff;
  minmax[1] = (int)0x80000000;
}

// ---------------- K4: MFMA sim -> global scratch (chunk of HC heads) --------
// Block = 16 q-rows of one head; wave w covers j in [w*256, (w+1)*256).
__global__ __launch_bounds__(256)
void sim_kernel(const _Float16* __restrict__ qh, const _Float16* __restrict__ ql,
                const _Float16* __restrict__ kh, const _Float16* __restrict__ kl,
                float* __restrict__ sim, int head_base, int HC) {
  int g = blockIdx.x;
  int bh_local, grp;
  if (HC >= 8) {          // XCD swizzle: a head's 64 blocks on one XCD
    int xcd = g & 7, slot = g >> 3;
    bh_local = (slot >> 6) * 8 + xcd;
    grp = slot & 63;
  } else {
    bh_local = g % HC;
    grp = g / HC;
  }
  int bh = head_base + bh_local;
  int tid = threadIdx.x, w = tid >> 6, l = tid & 63;
  int quad = l >> 4, lo16 = l & 15;
  size_t hb = (size_t)bh << 16;

  const _Float16* qhp = qh + hb + ((size_t)(grp * 16 + lo16) << 6);
  const _Float16* qlp = ql + hb + ((size_t)(grp * 16 + lo16) << 6);
  half8 ah0 = *(const half8*)(qhp + quad * 8);
  half8 ah1 = *(const half8*)(qhp + 32 + quad * 8);
  half8 al0 = *(const half8*)(qlp + quad * 8);
  half8 al1 = *(const half8*)(qlp + 32 + quad * 8);

  const _Float16* khp = kh + hb;
  const _Float16* klp = kl + hb;
  int jbase = w * 256;
  float* simr = sim + ((size_t)bh_local << 20);   // 1M elements per head

  half8 b0, b1, c0, c1, d0, d1, e0, e1;
  {
    size_t off = ((size_t)(jbase + lo16) << 6) + quad * 8;
    b0 = *(const half8*)(khp + off);
    b1 = *(const half8*)(khp + off + 32);
    c0 = *(const half8*)(klp + off);
    c1 = *(const half8*)(klp + off + 32);
  }
  #pragma unroll
  for (int tt = 0; tt < 16; ++tt) {
    if (tt + 1 < 16) {
      size_t off = ((size_t)(jbase + (tt + 1) * 16 + lo16) << 6) + quad * 8;
      d0 = *(const half8*)(khp + off);
      d1 = *(const half8*)(khp + off + 32);
      e0 = *(const half8*)(klp + off);
      e1 = *(const half8*)(klp + off + 32);
    }
    float4v acc = (float4v){0.f, 0.f, 0.f, 0.f};
    acc = mfma16(ah0, b0, acc);
    acc = mfma16(ah0, c0, acc);
    acc = mfma16(al0, b0, acc);
    acc = mfma16(ah1, b1, acc);
    acc = mfma16(ah1, c1, acc);
    acc = mfma16(al1, b1, acc);
    int jc = jbase + tt * 16 + lo16;
    #pragma unroll
    for (int rg = 0; rg < 4; ++rg)
      simr[((size_t)(grp * 16 + quad * 4 + rg) << 10) + jc] = acc[rg];
    b0 = d0; b1 = d1; c0 = e0; c1 = e1;
  }
}

// ---------------- K5: top-32 select + v gather-sum (1 row per wave) --------
__global__ __launch_bounds__(256)
void select_kernel(const float* __restrict__ sim, const float* __restrict__ vg,
                   float* __restrict__ xsum, int head_base, int HC) {
  __shared__ int sel[4][32];
  int g = blockIdx.x;                 // HC*256 blocks, 4 rows each
  int bh_local, rowgrp;
  if (HC >= 8) {                      // keep a head's v on one XCD's L2
    int xcd = g & 7, slot = g >> 3;
    bh_local = (slot >> 8) * 8 + xcd;
    rowgrp = slot & 255;
  } else {
    bh_local = g % HC;
    rowgrp = g / HC;
  }
  int bh = head_base + bh_local;
  int tid = threadIdx.x, w = tid >> 6, l = tid & 63;
  int row = rowgrp * 4 + w;
  size_t hb = (size_t)bh << 16;
  const float* sr = sim + ((size_t)bh_local << 20) + ((size_t)row << 10);
  unsigned long long below = (1ull << l) - 1ull;

  unsigned ku[16];
  #pragma unroll
  for (int s = 0; s < 16; ++s) ku[s] = fkey(sr[s * 64 + l]);

  // binary search for 32nd-largest key; early exit at exact count 32
  unsigned cur = 0u;
  bool exact = false;
  for (int bit = 31; bit >= 0; --bit) {
    unsigned T = cur | (1u << bit);
    int c = 0;
    #pragma unroll
    for (int s = 0; s < 16; ++s) c += __popcll(__ballot(ku[s] >= T));
    if (c >= 32) {
      cur = T;
      if (c == 32) { exact = true; break; }
    }
  }
  int need = 9999;
  if (!exact) {
    int gcnt = 0;
    #pragma unroll
    for (int s = 0; s < 16; ++s) gcnt += __popcll(__ballot(ku[s] > cur));
    need = 32 - gcnt;   // ties taken lowest-j first (jax tie-break)
  }

  int base = 0, eqb = 0;
  #pragma unroll
  for (int s = 0; s < 16; ++s) {
    bool gt = ku[s] > cur;
    bool eq = ku[s] == cur;
    unsigned long long meq = __ballot(eq);
    int eqr = eqb + __popcll(meq & below);
    bool take = gt || (eq && (eqr < need));
    unsigned long long mtk = __ballot(take);
    if (take) sel[w][base + __popcll(mtk & below)] = s * 64 + l;
    base += __popcll(mtk);
    eqb  += __popcll(meq);
  }

  const float* vb = vg + hb;
  float acc = 0.0f;
  #pragma unroll
  for (int s2 = 0; s2 < 32; ++s2) {
    int j = sel[w][s2];
    acc += vb[((size_t)j << 6) + l];
  }
  xsum[hb + ((size_t)row << 6) + l] = acc;
}

// ---------------- K6: global min/max reduce over xsum (256 blocks) ----------
__global__ __launch_bounds__(256)
void reduce_kernel(const float* __restrict__ xsum, int* __restrict__ minmax) {
  __shared__ float red[8];
  int tid = threadIdx.x, w = tid >> 6, l = tid & 63;
  const float4* p = (const float4*)xsum + (size_t)blockIdx.x * 4096 + tid;
  float mn = 3.4e38f, mx = -3.4e38f;
  #pragma unroll
  for (int i = 0; i < 16; ++i) {
    float4 v = p[(size_t)i * 256];
    mn = fminf(mn, fminf(fminf(v.x, v.y), fminf(v.z, v.w)));
    mx = fmaxf(mx, fmaxf(fmaxf(v.x, v.y), fmaxf(v.z, v.w)));
  }
  #pragma unroll
  for (int o = 32; o >= 1; o >>= 1) {
    mn = fminf(mn, __shfl_xor(mn, o, 64));
    mx = fmaxf(mx, __shfl_xor(mx, o, 64));
  }
  if (l == 0) { red[w*2] = mn; red[w*2+1] = mx; }
  __syncthreads();
  if (tid == 0) {
    mn = fminf(fminf(red[0], red[2]), fminf(red[4], red[6]));
    mx = fmaxf(fmaxf(red[1], red[3]), fmaxf(red[5], red[7]));
    atomicMin(minmax,     enc_i(mn));
    atomicMax(minmax + 1, enc_i(mx));
  }
}

// ---------------- K8: minmax-norm + exp + transpose -> f16 hi/lo ------------
__global__ __launch_bounds__(256)
void fin_kernel(const float* __restrict__ xsum, const int* __restrict__ minmax,
                _Float16* __restrict__ oh, _Float16* __restrict__ ol) {
  int idx = blockIdx.x * 256 + threadIdx.x;  // float4 index
  float mn = dec_i(minmax[0]);
  float mx = dec_i(minmax[1]);
  float inv = 1.0f / (mx - mn);
  float4 xv = ((const float4*)xsum)[idx];
  float o0 = expf((xv.x - mn) * inv);
  float o1 = expf((xv.y - mn) * inv);
  float o2 = expf((xv.z - mn) * inv);
  float o3 = expf((xv.w - mn) * inv);
  HL r0 = split2(o0), r1 = split2(o1), r2 = split2(o2), r3 = split2(o3);
  half4 hh = { r0.h, r1.h, r2.h, r3.h };
  half4 ll = { r0.l, r1.l, r2.l, r3.l };
  int e0 = idx << 2;
  int bh = e0 >> 16, i = (e0 >> 6) & 1023, dd = e0 & 63;
  int b = bh >> 4, h = bh & 15;
  size_t oe = ((size_t)(b * 1024 + i) << 10) + (h << 6) + dd;
  *(half4*)(oh + oe) = hh;
  *(half4*)(ol + oe) = ll;
}

// ---------------- launch ----------------
extern "C" void kernel_launch(void* const* d_in, const int* in_sizes, int n_in,
                              void* d_out, int out_size, void* d_ws, size_t ws_size,
                              hipStream_t stream) {
  const float* x     = (const float*)d_in[0];
  const float* gamma = (const float*)d_in[1];
  const float* beta  = (const float*)d_in[2];
  const float* w_qkv = (const float*)d_in[3];
  const float* w_out = (const float*)d_in[4];
  const float* b_out = (const float*)d_in[5];

  char* B = (char*)d_ws;
  const size_t MB = 1024ull * 1024ull;
  float*    v   = (float*)B;                        // 16 MB [bh][n][d]
  _Float16* qh  = (_Float16*)(B + 16*MB);           // 8 MB each plane
  _Float16* ql  = (_Float16*)(B + 24*MB);
  _Float16* kh  = (_Float16*)(B + 32*MB);
  _Float16* kl  = (_Float16*)(B + 40*MB);
  float*    xs  = (float*)(B + 48*MB);              // 16 MB (attn output)
  _Float16* xh  = (_Float16*)(B + 48*MB);           // LN planes (dead before xs)
  _Float16* xl  = (_Float16*)(B + 56*MB);
  _Float16* woh = (_Float16*)(B + 64*MB);           // 2 MB each
  _Float16* wol = (_Float16*)(B + 66*MB);
  int*   minmax = (int*)(B + 68*MB);
  _Float16* wqh = (_Float16*)(B + 69*MB);           // 6 MB each; dead after gemm0
  _Float16* wql = (_Float16*)(B + 75*MB);
  float*    sim = (float*)(B + 69*MB);              // overlaps wq planes (dead)
  _Float16* oth = qh;                               // reuse q planes after sim
  _Float16* otl = ql;

  // chunk the 256 MB sim scratch to fit ws_size (deterministic per deploy)
  size_t avail = (ws_size > 69*MB) ? ws_size - 69*MB : 0;
  int nch = 1;
  while (nch < 32 && (256/ (size_t)nch) * MB > avail) nch <<= 1;
  int HC = 64 / nch;                                // heads per chunk

  ln_kernel<<<4096, 256, 0, stream>>>(x, gamma, beta, xh, xl);
  cvt_kernel<<<4096, 256, 0, stream>>>(w_qkv, w_out, wqh, wql, woh, wol);
  gemm_f16split<0><<<dim3(24, 32), 256, 0, stream>>>(
      xh, xl, wqh, wql, nullptr, nullptr, qh, ql, kh, kl, v);
  init_kernel<<<1, 1, 0, stream>>>(minmax);
  for (int c = 0; c < nch; ++c) {
    sim_kernel<<<HC * 64, 256, 0, stream>>>(qh, ql, kh, kl, sim, c * HC, HC);
    select_kernel<<<HC * 256, 256, 0, stream>>>(sim, v, xs, c * HC, HC);
  }
  reduce_kernel<<<256, 256, 0, stream>>>(xs, minmax);
  fin_kernel<<<4096, 256, 0, stream>>>(xs, minmax, oth, otl);
  gemm_f16split<1><<<dim3(8, 32), 256, 0, stream>>>(
      oth, otl, woh, wol, b_out, (float*)d_out,
      nullptr, nullptr, nullptr, nullptr, nullptr);
}

// Round 9
// 427.293 us; speedup vs baseline: 1.6545x; 1.1641x over previous
//
#include <hip/hip_runtime.h>

// ProdAttention: LN -> QKV proj -> per-head top-32 of q.k^T (softmax monotone
// => select on raw sim) -> unweighted gather-sum of selected v rows -> global
// minmax-normalize + exp -> transpose -> output proj + bias.
// GEMM-shaped compute on MFMA with f16 hi/lo split (3 terms ~ fp32).
// R9: fused attn with 1024-thread blocks: 16 waves share the 66KB sim LDS ->
// 2 blocks/CU = 32 waves/CU (vs 8 in R7).  Each wave: 64-col MFMA strip,
// then selects ONE row (ballot binary search, exact jax tie-break).
// No global sim scratch, no chunk loop (R8's tiny launches were the loss).

#define LN_EPS 1e-5f

using half8   = __attribute__((ext_vector_type(8))) _Float16;
using half4   = __attribute__((ext_vector_type(4))) _Float16;
using float4v = __attribute__((ext_vector_type(4))) float;

__device__ __forceinline__ void gload_lds16(const void* g, void* l) {
  __builtin_amdgcn_global_load_lds(
      (const __attribute__((address_space(1))) void*)g,
      (__attribute__((address_space(3))) void*)l, 16, 0, 0);
}
__device__ __forceinline__ float4v mfma16(half8 a, half8 b, float4v c) {
  return __builtin_amdgcn_mfma_f32_16x16x32_f16(a, b, c, 0, 0, 0);
}
struct HL { _Float16 h, l; };
__device__ __forceinline__ HL split2(float x) {
  _Float16 h = (_Float16)x;
  return { h, (_Float16)(x - (float)h) };
}

// ---------------- order-preserving key helpers ----------------
__device__ __forceinline__ unsigned fkey(float f) {
  unsigned u = __float_as_uint(f);
  return ((int)u < 0) ? ~u : (u | 0x80000000u);
}
__device__ __forceinline__ int enc_i(float f) {
  int i = __float_as_int(f);
  return i >= 0 ? i : (i ^ 0x7fffffff);
}
__device__ __forceinline__ float dec_i(int e) {
  return __int_as_float(e >= 0 ? e : (e ^ 0x7fffffff));
}

// ---------------- K1: LayerNorm -> f16 hi/lo planes ----------------
__global__ __launch_bounds__(256)
void ln_kernel(const float* __restrict__ x, const float* __restrict__ gamma,
               const float* __restrict__ beta,
               _Float16* __restrict__ xh, _Float16* __restrict__ xl) {
  __shared__ float red[8];
  int row = blockIdx.x, t = threadIdx.x;
  const float4* xr = (const float4*)(x + (size_t)row * 1024);
  float4 v = xr[t];
  float s  = v.x + v.y + v.z + v.w;
  float s2 = v.x*v.x + v.y*v.y + v.z*v.z + v.w*v.w;
  #pragma unroll
  for (int o = 32; o >= 1; o >>= 1) {
    s  += __shfl_xor(s,  o, 64);
    s2 += __shfl_xor(s2, o, 64);
  }
  int w = t >> 6, l = t & 63;
  if (l == 0) { red[w*2] = s; red[w*2+1] = s2; }
  __syncthreads();
  float S  = red[0] + red[2] + red[4] + red[6];
  float S2 = red[1] + red[3] + red[5] + red[7];
  float mu  = S * (1.0f/1024.0f);
  float var = S2 * (1.0f/1024.0f) - mu*mu;
  float r = rsqrtf(var + LN_EPS);
  float4 g  = ((const float4*)gamma)[t];
  float4 bb = ((const float4*)beta)[t];
  float o0 = (v.x - mu) * r * g.x + bb.x;
  float o1 = (v.y - mu) * r * g.y + bb.y;
  float o2 = (v.z - mu) * r * g.z + bb.z;
  float o3 = (v.w - mu) * r * g.w + bb.w;
  HL r0 = split2(o0), r1 = split2(o1), r2 = split2(o2), r3 = split2(o3);
  half4 hh = { r0.h, r1.h, r2.h, r3.h };
  half4 ll = { r0.l, r1.l, r2.l, r3.l };
  size_t e = (size_t)row * 1024 + t*4;
  *(half4*)(xh + e) = hh;
  *(half4*)(xl + e) = ll;
}

// ---------------- K1b: weight fp32 -> f16 hi/lo planes ----------------
__global__ __launch_bounds__(256)
void cvt_kernel(const float* __restrict__ wqkv, const float* __restrict__ wout,
                _Float16* __restrict__ wqh, _Float16* __restrict__ wql,
                _Float16* __restrict__ woh, _Float16* __restrict__ wol) {
  size_t i4 = (size_t)blockIdx.x * 256 + threadIdx.x;   // float4 index, 1M total
  const float* src; _Float16 *dh, *dl; size_t off;
  if (i4 < 786432) { src = wqkv; dh = wqh; dl = wql; off = i4; }
  else             { src = wout; dh = woh; dl = wol; off = i4 - 786432; }
  float4 v = ((const float4*)src)[off];
  HL r0 = split2(v.x), r1 = split2(v.y), r2 = split2(v.z), r3 = split2(v.w);
  half4 hh = { r0.h, r1.h, r2.h, r3.h };
  half4 ll = { r0.l, r1.l, r2.l, r3.l };
  ((half4*)dh)[off] = hh;
  ((half4*)dl)[off] = ll;
}

// ---------------- K2/K7: f16-split MFMA NT GEMM, 128x128 tile ----------------
// C[m][n] = sum_k A[m][k]*B[n][k], A = Ah+Al, B = Bh+Bl (3 MFMA terms).
// MODE 0: scatter q,k -> f16 hi/lo planes [bh][n][d]; v -> fp32 [bh][n][d].
// MODE 1: CO = acc + bias (fp32).
template<int MODE>
__global__ __launch_bounds__(256)
void gemm_f16split(const _Float16* __restrict__ Ah, const _Float16* __restrict__ Al,
                   const _Float16* __restrict__ Bh, const _Float16* __restrict__ Bl,
                   const float* __restrict__ bias, float* __restrict__ CO,
                   _Float16* __restrict__ QH, _Float16* __restrict__ QL,
                   _Float16* __restrict__ KH, _Float16* __restrict__ KL,
                   float* __restrict__ CV) {
  __shared__ __align__(16) _Float16 lds[4 * 128 * 32];  // Ah | Al | Bh | Bl tiles
  const int K = 1024;
  int tid = threadIdx.x, w = tid >> 6, l = tid & 63;
  int m0 = blockIdx.y * 128, n0 = blockIdx.x * 128;
  int wm = (w >> 1) * 64, wn = (w & 1) * 64;

  const _Float16* src = (w == 0) ? Ah : (w == 1) ? Al : (w == 2) ? Bh : Bl;
  int rowbase = (w < 2) ? m0 : n0;
  _Float16* dst = lds + (size_t)w * 4096;
  int sr = l >> 2, sc = l & 3;

  float4v acc[4][4];
  #pragma unroll
  for (int u = 0; u < 4; ++u)
    #pragma unroll
    for (int vv = 0; vv < 4; ++vv) acc[u][vv] = (float4v){0.f, 0.f, 0.f, 0.f};

  int quad = l >> 4, lo16 = l & 15;
  for (int kt = 0; kt < K; kt += 32) {
    __syncthreads();
    #pragma unroll
    for (int i = 0; i < 8; ++i) {
      int row = i * 16 + sr;
      gload_lds16(src + (size_t)(rowbase + row) * K + kt + sc * 8,
                  dst + row * 32 + sc * 8);
    }
    __syncthreads();
    half8 ah[4], al[4], bh[4], bl[4];
    #pragma unroll
    for (int u = 0; u < 4; ++u) {
      int mrow = wm + u * 16 + lo16;
      int nrow = wn + u * 16 + lo16;
      ah[u] = *(const half8*)&lds[        (size_t)mrow * 32 + quad * 8];
      al[u] = *(const half8*)&lds[ 4096 + (size_t)mrow * 32 + quad * 8];
      bh[u] = *(const half8*)&lds[ 8192 + (size_t)nrow * 32 + quad * 8];
      bl[u] = *(const half8*)&lds[12288 + (size_t)nrow * 32 + quad * 8];
    }
    #pragma unroll
    for (int u = 0; u < 4; ++u)
      #pragma unroll
      for (int vv = 0; vv < 4; ++vv) {
        acc[u][vv] = mfma16(ah[u], bh[vv], acc[u][vv]);
        acc[u][vv] = mfma16(ah[u], bl[vv], acc[u][vv]);
        acc[u][vv] = mfma16(al[u], bh[vv], acc[u][vv]);
      }
  }

  // epilogue: C row = m ((lane>>4)*4+reg), col = n (lane&15)
  #pragma unroll
  for (int u = 0; u < 4; ++u) {
    #pragma unroll
    for (int vv = 0; vv < 4; ++vv) {
      #pragma unroll
      for (int rg = 0; rg < 4; ++rg) {
        int row = m0 + wm + u * 16 + quad * 4 + rg;
        int col = n0 + wn + vv * 16 + lo16;
        float val = acc[u][vv][rg];
        if (MODE == 0) {
          int which = col >> 10, h = (col >> 6) & 15, dd = col & 63;
          int b = row >> 10, i = row & 1023;
          size_t e = ((size_t)(b * 16 + h) << 16) + ((size_t)i << 6) + dd;
          if (which == 2) { CV[e] = val; }
          else {
            HL sp = split2(val);
            if (which == 0) { QH[e] = sp.h; QL[e] = sp.l; }
            else            { KH[e] = sp.h; KL[e] = sp.l; }
          }
        } else {
          CO[(size_t)row * 1024 + col] = val + bias[col];
        }
      }
    }
  }
}

// ---------------- K3 init ----------------
__global__ void init_kernel(int* minmax) {
  minmax[0] = 0x7fffffff;
  minmax[1] = (int)0x80000000;
}

// ---------------- K4: fused MFMA sim + top-32 select + v gather-sum ---------
// 1024-thread blocks (16 waves).  Wave w: 64-col sim strip (4 tiles x 6 MFMA)
// -> simb; barrier; wave w selects row w via ballot binary search (exact jax
// tie-break); gathers+sums 32 v rows.  LDS 68KB -> 2 blocks/CU = 32 waves/CU.
__global__ __launch_bounds__(1024)
void attn_kernel(const _Float16* __restrict__ qh, const _Float16* __restrict__ ql,
                 const _Float16* __restrict__ kh, const _Float16* __restrict__ kl,
                 const float* __restrict__ vg, float* __restrict__ xsum) {
  __shared__ float simb[16][1028];   // stride 1028: writes land 2-way max (free)
  __shared__ int sel[16][32];
  // XCD swizzle: all 64 row-blocks of a head on one XCD (k planes fit L2)
  int g = blockIdx.x;
  int xcd = g & 7, slot = g >> 3;
  int bh = (slot >> 6) * 8 + xcd, grp = slot & 63;
  int tid = threadIdx.x, w = tid >> 6, l = tid & 63;
  int quad = l >> 4, lo16 = l & 15;
  size_t hb = (size_t)bh << 16;

  // A-frags: q rows grp*16..+15 (same for all 16 waves; L1 broadcast)
  const _Float16* qhp = qh + hb + ((size_t)(grp * 16 + lo16) << 6);
  const _Float16* qlp = ql + hb + ((size_t)(grp * 16 + lo16) << 6);
  half8 ah0 = *(const half8*)(qhp + quad * 8);
  half8 ah1 = *(const half8*)(qhp + 32 + quad * 8);
  half8 al0 = *(const half8*)(qlp + quad * 8);
  half8 al1 = *(const half8*)(qlp + 32 + quad * 8);

  const _Float16* khp = kh + hb;
  const _Float16* klp = kl + hb;
  int jbase = w * 64;

  #pragma unroll
  for (int tt = 0; tt < 4; ++tt) {
    size_t off = ((size_t)(jbase + tt * 16 + lo16) << 6) + quad * 8;
    half8 b0 = *(const half8*)(khp + off);
    half8 b1 = *(const half8*)(khp + off + 32);
    half8 c0 = *(const half8*)(klp + off);
    half8 c1 = *(const half8*)(klp + off + 32);
    float4v acc = (float4v){0.f, 0.f, 0.f, 0.f};
    acc = mfma16(ah0, b0, acc);
    acc = mfma16(ah0, c0, acc);
    acc = mfma16(al0, b0, acc);
    acc = mfma16(ah1, b1, acc);
    acc = mfma16(ah1, c1, acc);
    acc = mfma16(al1, b1, acc);
    int jc = jbase + tt * 16 + lo16;
    #pragma unroll
    for (int rg = 0; rg < 4; ++rg)
      simb[quad * 4 + rg][jc] = acc[rg];
  }
  __syncthreads();

  // wave w selects row w
  unsigned long long below = (1ull << l) - 1ull;
  unsigned ku[16];
  #pragma unroll
  for (int s = 0; s < 16; ++s) ku[s] = fkey(simb[w][s * 64 + l]);

  // binary search for 32nd-largest key; early exit at exact count 32
  unsigned cur = 0u;
  bool exact = false;
  for (int bit = 31; bit >= 0; --bit) {
    unsigned T = cur | (1u << bit);
    int c = 0;
    #pragma unroll
    for (int s = 0; s < 16; ++s) c += __popcll(__ballot(ku[s] >= T));
    if (c >= 32) {
      cur = T;
      if (c == 32) { exact = true; break; }
    }
  }
  int need = 9999;
  if (!exact) {
    int gcnt = 0;
    #pragma unroll
    for (int s = 0; s < 16; ++s) gcnt += __popcll(__ballot(ku[s] > cur));
    need = 32 - gcnt;   // ties taken lowest-j first (jax tie-break)
  }

  int base = 0, eqb = 0;
  #pragma unroll
  for (int s = 0; s < 16; ++s) {
    bool gt = ku[s] > cur;
    bool eq = ku[s] == cur;
    unsigned long long meq = __ballot(eq);
    int eqr = eqb + __popcll(meq & below);
    bool take = gt || (eq && (eqr < need));
    unsigned long long mtk = __ballot(take);
    if (take) sel[w][base + __popcll(mtk & below)] = s * 64 + l;
    base += __popcll(mtk);
    eqb  += __popcll(meq);
  }

  const float* vb = vg + hb;
  float acc = 0.0f;
  #pragma unroll
  for (int s2 = 0; s2 < 32; ++s2) {
    int j = sel[w][s2];
    acc += vb[((size_t)j << 6) + l];
  }
  xsum[hb + ((size_t)(grp * 16 + w) << 6) + l] = acc;
}

// ---------------- K5: global min/max reduce over xsum (256 blocks) ----------
__global__ __launch_bounds__(256)
void reduce_kernel(const float* __restrict__ xsum, int* __restrict__ minmax) {
  __shared__ float red[8];
  int tid = threadIdx.x, w = tid >> 6, l = tid & 63;
  const float4* p = (const float4*)xsum + (size_t)blockIdx.x * 4096 + tid;
  float mn = 3.4e38f, mx = -3.4e38f;
  #pragma unroll
  for (int i = 0; i < 16; ++i) {
    float4 v = p[(size_t)i * 256];
    mn = fminf(mn, fminf(fminf(v.x, v.y), fminf(v.z, v.w)));
    mx = fmaxf(mx, fmaxf(fmaxf(v.x, v.y), fmaxf(v.z, v.w)));
  }
  #pragma unroll
  for (int o = 32; o >= 1; o >>= 1) {
    mn = fminf(mn, __shfl_xor(mn, o, 64));
    mx = fmaxf(mx, __shfl_xor(mx, o, 64));
  }
  if (l == 0) { red[w*2] = mn; red[w*2+1] = mx; }
  __syncthreads();
  if (tid == 0) {
    mn = fminf(fminf(red[0], red[2]), fminf(red[4], red[6]));
    mx = fmaxf(fmaxf(red[1], red[3]), fmaxf(red[5], red[7]));
    atomicMin(minmax,     enc_i(mn));
    atomicMax(minmax + 1, enc_i(mx));
  }
}

// ---------------- K6: minmax-norm + exp + transpose -> f16 hi/lo ------------
__global__ __launch_bounds__(256)
void fin_kernel(const float* __restrict__ xsum, const int* __restrict__ minmax,
                _Float16* __restrict__ oh, _Float16* __restrict__ ol) {
  int idx = blockIdx.x * 256 + threadIdx.x;  // float4 index
  float mn = dec_i(minmax[0]);
  float mx = dec_i(minmax[1]);
  float inv = 1.0f / (mx - mn);
  float4 xv = ((const float4*)xsum)[idx];
  float o0 = expf((xv.x - mn) * inv);
  float o1 = expf((xv.y - mn) * inv);
  float o2 = expf((xv.z - mn) * inv);
  float o3 = expf((xv.w - mn) * inv);
  HL r0 = split2(o0), r1 = split2(o1), r2 = split2(o2), r3 = split2(o3);
  half4 hh = { r0.h, r1.h, r2.h, r3.h };
  half4 ll = { r0.l, r1.l, r2.l, r3.l };
  int e0 = idx << 2;
  int bh = e0 >> 16, i = (e0 >> 6) & 1023, dd = e0 & 63;
  int b = bh >> 4, h = bh & 15;
  size_t oe = ((size_t)(b * 1024 + i) << 10) + (h << 6) + dd;
  *(half4*)(oh + oe) = hh;
  *(half4*)(ol + oe) = ll;
}

// ---------------- launch ----------------
extern "C" void kernel_launch(void* const* d_in, const int* in_sizes, int n_in,
                              void* d_out, int out_size, void* d_ws, size_t ws_size,
                              hipStream_t stream) {
  const float* x     = (const float*)d_in[0];
  const float* gamma = (const float*)d_in[1];
  const float* beta  = (const float*)d_in[2];
  const float* w_qkv = (const float*)d_in[3];
  const float* w_out = (const float*)d_in[4];
  const float* b_out = (const float*)d_in[5];

  char* B = (char*)d_ws;
  const size_t MB = 1024ull * 1024ull;
  float*    v   = (float*)B;                        // 16 MB [bh][n][d]
  _Float16* qh  = (_Float16*)(B + 16*MB);           // 8 MB each plane
  _Float16* ql  = (_Float16*)(B + 24*MB);
  _Float16* kh  = (_Float16*)(B + 32*MB);
  _Float16* kl  = (_Float16*)(B + 40*MB);
  float*    xs  = (float*)(B + 48*MB);              // 16 MB (attn output)
  _Float16* xh  = (_Float16*)(B + 48*MB);           // LN planes (dead before xs)
  _Float16* xl  = (_Float16*)(B + 56*MB);
  _Float16* woh = (_Float16*)(B + 64*MB);           // 2 MB each
  _Float16* wol = (_Float16*)(B + 66*MB);
  int*   minmax = (int*)(B + 68*MB);
  _Float16* wqh = (_Float16*)(B + 69*MB);           // 6 MB each
  _Float16* wql = (_Float16*)(B + 75*MB);
  _Float16* oth = qh;                               // reuse q planes after attn
  _Float16* otl = ql;

  ln_kernel<<<4096, 256, 0, stream>>>(x, gamma, beta, xh, xl);
  cvt_kernel<<<4096, 256, 0, stream>>>(w_qkv, w_out, wqh, wql, woh, wol);
  gemm_f16split<0><<<dim3(24, 32), 256, 0, stream>>>(
      xh, xl, wqh, wql, nullptr, nullptr, qh, ql, kh, kl, v);
  init_kernel<<<1, 1, 0, stream>>>(minmax);
  attn_kernel<<<4096, 1024, 0, stream>>>(qh, ql, kh, kl, v, xs);
  reduce_kernel<<<256, 256, 0, stream>>>(xs, minmax);
  fin_kernel<<<4096, 256, 0, stream>>>(xs, minmax, oth, otl);
  gemm_f16split<1><<<dim3(8, 32), 256, 0, stream>>>(
      oth, otl, woh, wol, b_out, (float*)d_out,
      nullptr, nullptr, nullptr, nullptr, nullptr);
}